// Round 10
// baseline (262.371 us; speedup 1.0000x reference)
//
#include <hip/hip_runtime.h>

#define G 128
// bitmap: 2*128^3 bits = 512 KB (cleared each launch); table: 16 MB (never cleared)
#define BITMAP_BYTES (2u * G * G * G / 8u)

typedef float nfloat4 __attribute__((ext_vector_type(4)));  // native vec for nt-store

__global__ void build_kernel(const int4* __restrict__ coords,
                             unsigned* __restrict__ bitmap,
                             int* __restrict__ table, int n) {
    int i = blockIdx.x * blockDim.x + threadIdx.x;
    if (i >= n) return;
    int4 c = coords[i];
    int key = (c.x << 21) | (c.y << 14) | (c.z << 7) | c.w;
    table[key] = i;
    atomicOr(&bitmap[key >> 5], 1u << (key & 31));
}

// Apply one shared hit (packed p) to the accumulators.
#define APPLY_HIT(p)                                                        \
    {                                                                       \
        int idx = (int)((p) >> 8) - 1;                                      \
        unsigned om = (p) & 255u;                                           \
        int pc = __popc(om);                                                \
        float w = (pc == 4) ? 0.140625f : ((pc == 2) ? 0.046875f : 0.015625f); \
        float4 g4 = feats[(size_t)idx * 16 + cg];                           \
        float ddx = w * (g4.x - d4.x), ddy = w * (g4.y - d4.y);             \
        float ddz = w * (g4.z - d4.z), ddw = w * (g4.w - d4.w);             \
        _Pragma("unroll")                                                   \
        for (int o = 0; o < 8; ++o) {                                       \
            float s = (float)((om >> o) & 1u);                              \
            acc[o].x += s * ddx; acc[o].y += s * ddy;                       \
            acc[o].z += s * ddz; acc[o].w += s * ddw;                       \
        }                                                                   \
    }

__global__ __launch_bounds__(256) void upsample_kernel(
        const int4* __restrict__ coords,
        const float4* __restrict__ feats,   // N x 16 float4
        const float4* __restrict__ dflt,    // 16 float4
        const unsigned* __restrict__ bitmap,
        const int* __restrict__ table,
        float4* __restrict__ out,           // (N*8) x 16 float4
        int n) {
    int t = blockIdx.x * blockDim.x + threadIdx.x;
    int i = t >> 4;           // point index (16 lanes per point)
    int cg = t & 15;          // float4 channel group
    if (i >= n) return;
    int lane = threadIdx.x & 63;
    int g = lane >> 4;        // group within wave (4 points per wave)
    int l = lane & 15;        // lane within group

    int4 c = coords[i];
    int x = c.y, y = c.z, z = c.w;
    int bbase = c.x << 21;

    // ---- probe phase: lanes 0..12 each probe directions l and l+14 (center=13 skipped)
    unsigned packed0 = 0u, packed1 = 0u;
    if (l < 13) {
        #pragma unroll
        for (int r = 0; r < 2; ++r) {
            int di = l + (r ? 14 : 0);
            int ex = di / 9 - 1;
            int ey = (di / 3) % 3 - 1;
            int ez = di % 3 - 1;
            int nx = x + ex, ny = y + ey, nz = z + ez;
            bool valid = ((unsigned)nx < G) & ((unsigned)ny < G) & ((unsigned)nz < G);
            int key = valid ? (bbase | (nx << 14) | (ny << 7) | nz) : bbase;
            unsigned wrd = bitmap[key >> 5];
            unsigned p = 0u;
            if (valid && ((wrd >> (key & 31)) & 1u)) {
                int idx = table[key];
                // 2-bit per-axis octant masks: -1 -> {0}, 0 -> {0,1}, +1 -> {1}
                unsigned xm = (ex == 0) ? 3u : ((ex < 0) ? 1u : 2u);
                unsigned ym = (ey == 0) ? 3u : ((ey < 0) ? 1u : 2u);
                unsigned zm = (ez == 0) ? 3u : ((ez < 0) ? 1u : 2u);
                unsigned myz = ((ym & 1u) ? zm : 0u) | ((ym & 2u) ? (zm << 2) : 0u);
                unsigned om  = ((xm & 1u) ? myz : 0u) | ((xm & 2u) ? (myz << 4) : 0u);
                p = ((unsigned)(idx + 1) << 8) | om;
            }
            if (r) packed1 = p; else packed0 = p;
        }
    }
    unsigned long long bal0 = __ballot(packed0 != 0u);
    unsigned long long bal1 = __ballot(packed1 != 0u);

    // ---- base: default + parent contribution (weight 0.75^3 for all 8 octants)
    float4 d4 = dflt[cg];
    float4 f4 = feats[(size_t)i * 16 + cg];
    float4 base;
    base.x = d4.x + 0.421875f * (f4.x - d4.x);
    base.y = d4.y + 0.421875f * (f4.y - d4.y);
    base.z = d4.z + 0.421875f * (f4.z - d4.z);
    base.w = d4.w + 0.421875f * (f4.w - d4.w);
    float4 acc[8];
    #pragma unroll
    for (int o = 0; o < 8; ++o) acc[o] = base;

    // ---- apply phase: iterate this group's hits (expected ~0.6 per point)
    unsigned m0 = (unsigned)((bal0 >> (g * 16)) & 0x1FFFull);
    unsigned m1 = (unsigned)((bal1 >> (g * 16)) & 0x1FFFull);
    while (m0) {
        int j = __ffs(m0) - 1; m0 &= m0 - 1;
        unsigned p = (unsigned)__shfl((int)packed0, (g << 4) + j, 64);
        APPLY_HIT(p);
    }
    while (m1) {
        int j = __ffs(m1) - 1; m1 &= m1 - 1;
        unsigned p = (unsigned)__shfl((int)packed1, (g << 4) + j, 64);
        APPLY_HIT(p);
    }

    // ---- nontemporal stores: out is write-once, keep it out of L2 so the
    // bitmap/table/feats probe structures stay resident. Cast to a native
    // ext_vector type: __builtin_nontemporal_store rejects HIP_vector_type.
    size_t rbase = (size_t)i * 128 + cg;   // in float4 units
    nfloat4* outn = (nfloat4*)out;
    #pragma unroll
    for (int o = 0; o < 8; ++o) {
        nfloat4 v = {acc[o].x, acc[o].y, acc[o].z, acc[o].w};
        __builtin_nontemporal_store(v, &outn[rbase + o * 16]);
    }
}

extern "C" void kernel_launch(void* const* d_in, const int* in_sizes, int n_in,
                              void* d_out, int out_size, void* d_ws, size_t ws_size,
                              hipStream_t stream) {
    const int4*   coords = (const int4*)d_in[0];
    const float4* feats  = (const float4*)d_in[1];
    const float4* dflt   = (const float4*)d_in[2];
    float4*       out    = (float4*)d_out;
    int n = in_sizes[0] / 4;

    unsigned* bitmap = (unsigned*)d_ws;
    int* table = (int*)((char*)d_ws + BITMAP_BYTES);   // read only where bitmap bit set

    (void)hipMemsetAsync(bitmap, 0, BITMAP_BYTES, stream);   // 512 KB only
    build_kernel<<<(n + 255) / 256, 256, 0, stream>>>(coords, bitmap, table, n);

    long long total = (long long)n * 16;               // 16 lanes per point
    int blocks = (int)((total + 255) / 256);
    upsample_kernel<<<blocks, 256, 0, stream>>>(coords, feats, dflt, bitmap, table, out, n);
}